// Round 10
// baseline (891.900 us; speedup 1.0000x reference)
//
#include <hip/hip_runtime.h>

#define NH 6
#define NTOK 49
#define CDIM 192
#define NWIN 1024
#define SCALE 0.17677669529663687f

typedef __bf16 bf16x8 __attribute__((ext_vector_type(8)));
typedef float f32x4 __attribute__((ext_vector_type(4)));
typedef unsigned short u16;
typedef unsigned int u32;

__device__ __forceinline__ u16 bfr(float x) { return __builtin_bit_cast(u16, (__bf16)x); }

__global__ void build_wb(const float* __restrict__ w, u16* __restrict__ wb) {
    int i = blockIdx.x * 256 + threadIdx.x;
    if (i < CDIM * CDIM) wb[i] = bfr(w[i]);
}

// Fused window attention + proj. One block per window, 256 thr = 4 waves.
// R10: NO K/V LDS staging -- K and V MFMA fragments load direct global->reg
// (4 waves read the same lines; L1/L2 absorb the redundancy, proven R3/R5:
// FETCH 491 vs 493 MB). Head loop has ZERO barriers; only wave-private LDS
// (P stripe + xb rows). ONE __syncthreads total, before the proj tail.
// Swapped QK^T (R9): lane holds q-row 16wv+lc, k = 16t+4lg+r; softmax =
// local tree + 2 shfl_xor. LDS = xb 25600 + stripes 9216 = 34816 B.
__global__ __launch_bounds__(256, 4)
void swin_fused(const float* __restrict__ qkv, const int* __restrict__ rpi,
                const float* __restrict__ mask, const float* __restrict__ bias_table,
                const u16* __restrict__ wb, const float* __restrict__ proj_b,
                float* __restrict__ out) {
    __shared__ u16 xb_s[64][200];     // x (all heads) bf16; rows wave-private until barrier
    __shared__ u16 p_s[4][16][72];    // per-wave P stripe (wave-private, no sync)

    const int tid = threadIdx.x;
    const int b = blockIdx.x;
    const int wn = b & (NWIN - 1);
    const int wv = tid >> 6;
    const int lane = tid & 63;
    const int lg = lane >> 4;
    const int lc = lane & 15;

    const float* qkvb = qkv + (size_t)b * (NTOK * 3 * CDIM);
    const float* mrow = mask + (size_t)wn * (NTOK * NTOK);
    const f32x4 fzero = {0.f, 0.f, 0.f, 0.f};

    // per-lane Q row pointer (clamped; pad rows masked later)
    const int qrow = (16 * wv + lc < NTOK) ? 16 * wv + lc : NTOK - 1;
    const float* qptr = qkvb + (size_t)qrow * 576 + 8 * lg;
    // per-lane K row pointers for the 4 k-tiles (clamped)
    const float* kptr[4];
#pragma unroll
    for (int t = 0; t < 4; ++t) {
        const int krow = (16 * t + lc < NTOK) ? 16 * t + lc : NTOK - 1;
        kptr[t] = qkvb + (size_t)krow * 576 + CDIM + 8 * lg;
    }
    // per-lane V row offsets for the B-frag reads: k = 32ks + 8lg + j (clamped)
    // element addr = qkvb + krow*576 + 384 + 32h + 16ct + lc
    const float* vptr[2];  // [ks] base at j=0 (row clamp applied per j below)
    int vrow[2][8];
#pragma unroll
    for (int ks = 0; ks < 2; ++ks)
#pragma unroll
        for (int j = 0; j < 8; ++j) {
            const int r = 32 * ks + 8 * lg + j;
            vrow[ks][j] = (r < NTOK ? r : NTOK - 1) * 576;
        }
    vptr[0] = qkvb + 2 * CDIM + lc;
    vptr[1] = qkvb + 2 * CDIM + lc;

    // ---- issue h=0 Q load ----
    float4 qfA = *reinterpret_cast<const float4*>(qptr);
    float4 qfB = *reinterpret_cast<const float4*>(qptr + 4);

    // ---- hoist per-lane rpi/mask: q = 16wv+lc, k = 16t+4lg+r ----
    int bofs[4][4];
    float maddf[4][4];
    {
        const int i = 16 * wv + lc;
#pragma unroll
        for (int t = 0; t < 4; ++t)
#pragma unroll
            for (int r = 0; r < 4; ++r) {
                const int j = 16 * t + 4 * lg + r;
                const bool valid = (i < NTOK) && (j < NTOK);
                const int ij = valid ? i * NTOK + j : 0;
                bofs[t][r] = rpi[ij] * NH;
                maddf[t][r] = valid ? mrow[ij] : -1e30f;
            }
    }

#pragma unroll
    for (int h = 0; h < NH; ++h) {
        // ---- issue K fragment loads (direct global, 4 frags x 32B) ----
        float4 kfA[4], kfB[4];
#pragma unroll
        for (int t = 0; t < 4; ++t) {
            kfA[t] = *reinterpret_cast<const float4*>(kptr[t] + h * 32);
            kfB[t] = *reinterpret_cast<const float4*>(kptr[t] + h * 32 + 4);
        }
        // ---- issue V fragment loads (direct global; lanes lc -> 64B segments) ----
        float vf[2][2][8];  // [ct][ks][j]
#pragma unroll
        for (int ct = 0; ct < 2; ++ct)
#pragma unroll
            for (int ks = 0; ks < 2; ++ks)
#pragma unroll
                for (int j = 0; j < 8; ++j)
                    vf[ct][ks][j] = vptr[ks][vrow[ks][j] + h * 32 + 16 * ct];

        // ---- bias gather (L1-resident table) ----
        float bias_v[4][4];
#pragma unroll
        for (int t = 0; t < 4; ++t)
#pragma unroll
            for (int r = 0; r < 4; ++r)
                bias_v[t][r] = bias_table[bofs[t][r] + h];

        // ---- Q fragment from prefetched regs; prefetch Q(h+1) ----
        bf16x8 aq;
        aq[0] = (__bf16)(qfA.x * SCALE); aq[1] = (__bf16)(qfA.y * SCALE);
        aq[2] = (__bf16)(qfA.z * SCALE); aq[3] = (__bf16)(qfA.w * SCALE);
        aq[4] = (__bf16)(qfB.x * SCALE); aq[5] = (__bf16)(qfB.y * SCALE);
        aq[6] = (__bf16)(qfB.z * SCALE); aq[7] = (__bf16)(qfB.w * SCALE);
        if (h + 1 < NH) {
            qfA = *reinterpret_cast<const float4*>(qptr + (h + 1) * 32);
            qfB = *reinterpret_cast<const float4*>(qptr + (h + 1) * 32 + 4);
        }

        // ---- K cvt + swapped QK^T: lane holds q-row 16wv+lc, k=16t+4lg+r ----
        f32x4 acc[4];
#pragma unroll
        for (int t = 0; t < 4; ++t) {
            bf16x8 bk;
            bk[0] = (__bf16)kfA[t].x; bk[1] = (__bf16)kfA[t].y;
            bk[2] = (__bf16)kfA[t].z; bk[3] = (__bf16)kfA[t].w;
            bk[4] = (__bf16)kfB[t].x; bk[5] = (__bf16)kfB[t].y;
            bk[6] = (__bf16)kfB[t].z; bk[7] = (__bf16)kfB[t].w;
            acc[t] = __builtin_amdgcn_mfma_f32_16x16x32_bf16(bk, aq, fzero, 0, 0, 0);
        }

        // ---- softmax: lane-local tree + 2 shfl for max and sum ----
        float vals[4][4];
#pragma unroll
        for (int t = 0; t < 4; ++t)
#pragma unroll
            for (int r = 0; r < 4; ++r)
                vals[t][r] = acc[t][r] + bias_v[t][r] + maddf[t][r];

        float mx[4];
#pragma unroll
        for (int t = 0; t < 4; ++t)
            mx[t] = fmaxf(fmaxf(vals[t][0], vals[t][1]), fmaxf(vals[t][2], vals[t][3]));
        float m = fmaxf(fmaxf(mx[0], mx[1]), fmaxf(mx[2], mx[3]));
        m = fmaxf(m, __shfl_xor(m, 16));
        m = fmaxf(m, __shfl_xor(m, 32));

        float e[4][4];
        float s = 0.f;
#pragma unroll
        for (int t = 0; t < 4; ++t) {
            float st = 0.f;
#pragma unroll
            for (int r = 0; r < 4; ++r) { e[t][r] = __expf(vals[t][r] - m); st += e[t][r]; }
            s += st;
        }
        s += __shfl_xor(s, 16);
        s += __shfl_xor(s, 32);
        const float rs = 1.0f / s;

        // ---- packed P store into wave-private stripe (no sync needed) ----
        {
            u16* prow = &p_s[wv][lc][4 * lg];
#pragma unroll
            for (int t = 0; t < 4; ++t) {
                ushort4 pk;
                pk.x = bfr(e[t][0] * rs); pk.y = bfr(e[t][1] * rs);
                pk.z = bfr(e[t][2] * rs); pk.w = bfr(e[t][3] * rs);
                *reinterpret_cast<ushort4*>(prow + 16 * t) = pk;
            }
        }

        // ---- V cvt (loads issued at top: ~full head of cover) ----
        bf16x8 vv[2][2];
#pragma unroll
        for (int ct = 0; ct < 2; ++ct)
#pragma unroll
            for (int ks = 0; ks < 2; ++ks)
#pragma unroll
                for (int j = 0; j < 8; ++j)
                    vv[ct][ks][j] = (__bf16)vf[ct][ks][j];

        // ---- PV: x_h[16x32] per wave ----
        f32x4 xacc[2] = {fzero, fzero};
#pragma unroll
        for (int ks = 0; ks < 2; ++ks) {
            const bf16x8 pa = *reinterpret_cast<const bf16x8*>(&p_s[wv][lc][32 * ks + 8 * lg]);
#pragma unroll
            for (int ct = 0; ct < 2; ++ct)
                xacc[ct] = __builtin_amdgcn_mfma_f32_16x16x32_bf16(pa, vv[ct][ks], xacc[ct], 0, 0, 0);
        }

        // ---- x_h -> xb (wave-private rows 16wv..16wv+15) ----
#pragma unroll
        for (int ct = 0; ct < 2; ++ct)
#pragma unroll
            for (int r = 0; r < 4; ++r)
                xb_s[16 * wv + 4 * lg + r][32 * h + 16 * ct + lc] = bfr(xacc[ct][r]);
    }

    __syncthreads();  // the ONLY barrier: xb complete -> proj

    // ---- proj: out = x @ W^T + b; wave wv owns cols 48wv..48wv+47 ----
    f32x4 pacc[3][4];
#pragma unroll
    for (int ct = 0; ct < 3; ++ct)
#pragma unroll
        for (int rt = 0; rt < 4; ++rt) pacc[ct][rt] = fzero;

#pragma unroll
    for (int ks = 0; ks < 6; ++ks) {
        bf16x8 af[4];
#pragma unroll
        for (int rt = 0; rt < 4; ++rt)
            af[rt] = *reinterpret_cast<const bf16x8*>(&xb_s[16 * rt + lc][32 * ks + 8 * lg]);
#pragma unroll
        for (int ct = 0; ct < 3; ++ct) {
            const int c = 48 * wv + 16 * ct + lc;
            const bf16x8 bw = *reinterpret_cast<const bf16x8*>(wb + c * CDIM + 32 * ks + 8 * lg);
#pragma unroll
            for (int rt = 0; rt < 4; ++rt)
                pacc[ct][rt] = __builtin_amdgcn_mfma_f32_16x16x32_bf16(af[rt], bw, pacc[ct][rt], 0, 0, 0);
        }
    }

#pragma unroll
    for (int ct = 0; ct < 3; ++ct) {
        const int c = 48 * wv + 16 * ct + lc;
        const float pb = proj_b[c];
#pragma unroll
        for (int rt = 0; rt < 4; ++rt) {
#pragma unroll
            for (int r = 0; r < 4; ++r) {
                const int i = 16 * rt + 4 * lg + r;
                if (i < NTOK)
                    out[(size_t)b * (NTOK * CDIM) + i * CDIM + c] = pacc[ct][rt][r] + pb;
            }
        }
    }
}

extern "C" void kernel_launch(void* const* d_in, const int* in_sizes, int n_in,
                              void* d_out, int out_size, void* d_ws, size_t ws_size,
                              hipStream_t stream) {
    const float* qkv        = (const float*)d_in[0];
    const int*   rpi        = (const int*)d_in[1];
    const float* mask       = (const float*)d_in[2];
    const float* bias_table = (const float*)d_in[3];
    const float* proj_w     = (const float*)d_in[4];
    const float* proj_b     = (const float*)d_in[5];
    float* out = (float*)d_out;
    u16* wb = (u16*)d_ws;  // bf16 copy of proj_w (73728 B)

    const int nblk = in_sizes[0] / (NTOK * 3 * CDIM);  // 8192 windows

    build_wb<<<(CDIM * CDIM + 255) / 256, 256, 0, stream>>>(proj_w, wb);
    swin_fused<<<nblk, 256, 0, stream>>>(qkv, rpi, mask, bias_table, wb, proj_b, out);
}

// Round 11
// 703.167 us; speedup vs baseline: 1.2684x; 1.2684x over previous
//
#include <hip/hip_runtime.h>

#define NH 6
#define NTOK 49
#define CDIM 192
#define NWIN 1024
#define SCALE 0.17677669529663687f

typedef __bf16 bf16x8 __attribute__((ext_vector_type(8)));
typedef float f32x4 __attribute__((ext_vector_type(4)));
typedef unsigned short u16;
typedef unsigned int u32;

__device__ __forceinline__ u16 bfr(float x) { return __builtin_bit_cast(u16, (__bf16)x); }

__global__ void build_wb(const float* __restrict__ w, u16* __restrict__ wb) {
    int i = blockIdx.x * 256 + threadIdx.x;
    if (i < CDIM * CDIM) wb[i] = bfr(w[i]);
}

// Fused window attention + proj. One block per window, 256 thr = 4 waves.
// R11: ALL V staged ONCE up front (all 6 heads, one deep load burst) into
// vT_s[6][32][72]; K direct global->reg prefetched 1 head ahead (R5-proven:
// wave-redundant K reads are L1/L2-absorbed, zero FETCH cost); Q prefetched.
// Head loop contains NO staging and NO barriers -- one __syncthreads total
// (after V stage). P/x via wave-private LDS stripes; x_h kept as reg
// A-fragments af[6]; proj tail after the single barrier... (proj needs no
// barrier at all: af is per-wave). Swapped QK^T softmax (R9).
// LDS = 27648(vT) + 9216(p stripes) = 36864 B -> 4 blocks/CU.
__global__ __launch_bounds__(256, 4)
void swin_fused(const float* __restrict__ qkv, const int* __restrict__ rpi,
                const float* __restrict__ mask, const float* __restrict__ bias_table,
                const u16* __restrict__ wb, const float* __restrict__ proj_b,
                float* __restrict__ out) {
    __shared__ u16 vT_s[NH][32][72];  // V^T bf16 [h][d][n]; pad cols zeroed
    __shared__ u16 p_s[4][16][72];    // per-wave P / x_h stripe (wave-private)

    const int tid = threadIdx.x;
    const int b = blockIdx.x;
    const int wn = b & (NWIN - 1);
    const int wv = tid >> 6;
    const int lane = tid & 63;
    const int lg = lane >> 4;
    const int lc = lane & 15;

    const float* qkvb = qkv + (size_t)b * (NTOK * 3 * CDIM);
    const float* mrow = mask + (size_t)wn * (NTOK * NTOK);
    const f32x4 fzero = {0.f, 0.f, 0.f, 0.f};

    // per-lane Q row pointer (clamped; pad rows masked later)
    const int qrow = (16 * wv + lc < NTOK) ? 16 * wv + lc : NTOK - 1;
    const float* qptr = qkvb + (size_t)qrow * 576 + 8 * lg;
    // per-lane K row pointers for the 4 k-tiles (clamped; dup rows killed by madd)
    const float* kptr[4];
#pragma unroll
    for (int t = 0; t < 4; ++t) {
        const int krow = (16 * t + lc < NTOK) ? 16 * t + lc : NTOK - 1;
        kptr[t] = qkvb + (size_t)krow * 576 + CDIM + 8 * lg;
    }

    // ---- issue h=0 Q and K loads (land during setup below) ----
    float4 qfA = *reinterpret_cast<const float4*>(qptr);
    float4 qfB = *reinterpret_cast<const float4*>(qptr + 4);
    float4 kfA[4], kfB[4];
#pragma unroll
    for (int t = 0; t < 4; ++t) {
        kfA[t] = *reinterpret_cast<const float4*>(kptr[t]);
        kfB[t] = *reinterpret_cast<const float4*>(kptr[t] + 4);
    }

    // ---- hoist per-lane rpi/mask: q = 16wv+lc, k = 16t+4lg+r ----
    int bofs[4][4];
    float maddf[4][4];
    {
        const int i = 16 * wv + lc;
#pragma unroll
        for (int t = 0; t < 4; ++t)
#pragma unroll
            for (int r = 0; r < 4; ++r) {
                const int j = 16 * t + 4 * lg + r;
                const bool valid = (i < NTOK) && (j < NTOK);
                const int ij = valid ? i * NTOK + j : 0;
                bofs[t][r] = rpi[ij] * NH;
                maddf[t][r] = valid ? mrow[ij] : -1e30f;
            }
    }

    // ---- stage ALL V (6 heads) once: 2352 float4s, ~9/thread, one burst ----
#pragma unroll
    for (int k = 0; k < 10; ++k) {
        const int idx = tid + 256 * k;
        if (idx < 2352) {
            const int n = idx / 48;       // token row
            const int f = idx % 48;       // float4 within row (192 floats)
            const float4 v4 = *reinterpret_cast<const float4*>(qkvb + n * 576 + 2 * CDIM + 4 * f);
            const int h = f >> 3;
            const int d = 4 * (f & 7);
            vT_s[h][d + 0][n] = bfr(v4.x);
            vT_s[h][d + 1][n] = bfr(v4.y);
            vT_s[h][d + 2][n] = bfr(v4.z);
            vT_s[h][d + 3][n] = bfr(v4.w);
        }
    }
    // ---- zero vT pad cols 49..63 for all heads (NaN-proof PV) ----
#pragma unroll
    for (int k = 0; k < 12; ++k) {
        const int idx = tid + 256 * k;
        if (idx < NH * 32 * 15) {
            const int h = idx / 480;
            const int r = idx % 480;
            vT_s[h][r / 15][49 + (r % 15)] = 0;
        }
    }
    __syncthreads();  // the ONLY barrier: vT ready for all heads

    bf16x8 af[NH];  // x_h A-fragments (static index via full unroll)

#pragma unroll
    for (int h = 0; h < NH; ++h) {
        // ---- cvt this head's Q/K from prefetched regs ----
        bf16x8 aq;
        aq[0] = (__bf16)(qfA.x * SCALE); aq[1] = (__bf16)(qfA.y * SCALE);
        aq[2] = (__bf16)(qfA.z * SCALE); aq[3] = (__bf16)(qfA.w * SCALE);
        aq[4] = (__bf16)(qfB.x * SCALE); aq[5] = (__bf16)(qfB.y * SCALE);
        aq[6] = (__bf16)(qfB.z * SCALE); aq[7] = (__bf16)(qfB.w * SCALE);
        bf16x8 bk[4];
#pragma unroll
        for (int t = 0; t < 4; ++t) {
            bk[t][0] = (__bf16)kfA[t].x; bk[t][1] = (__bf16)kfA[t].y;
            bk[t][2] = (__bf16)kfA[t].z; bk[t][3] = (__bf16)kfA[t].w;
            bk[t][4] = (__bf16)kfB[t].x; bk[t][5] = (__bf16)kfB[t].y;
            bk[t][6] = (__bf16)kfB[t].z; bk[t][7] = (__bf16)kfB[t].w;
        }

        // ---- issue Q/K prefetch for h+1 (covered by softmax+PV ~1k cyc) ----
        if (h + 1 < NH) {
            qfA = *reinterpret_cast<const float4*>(qptr + (h + 1) * 32);
            qfB = *reinterpret_cast<const float4*>(qptr + (h + 1) * 32 + 4);
#pragma unroll
            for (int t = 0; t < 4; ++t) {
                kfA[t] = *reinterpret_cast<const float4*>(kptr[t] + (h + 1) * 32);
                kfB[t] = *reinterpret_cast<const float4*>(kptr[t] + (h + 1) * 32 + 4);
            }
        }

        // ---- bias gather (L1-resident table) ----
        float bias_v[4][4];
#pragma unroll
        for (int t = 0; t < 4; ++t)
#pragma unroll
            for (int r = 0; r < 4; ++r)
                bias_v[t][r] = bias_table[bofs[t][r] + h];

        // ---- swapped QK^T: lane holds q-row 16wv+lc, k = 16t+4lg+r ----
        f32x4 acc[4];
#pragma unroll
        for (int t = 0; t < 4; ++t)
            acc[t] = __builtin_amdgcn_mfma_f32_16x16x32_bf16(bk[t], aq, fzero, 0, 0, 0);

        // ---- hoist V fragment reads (independent of softmax; DS latency
        //      hides under the softmax VALU chain) ----
        bf16x8 vv[2][2];
#pragma unroll
        for (int ct = 0; ct < 2; ++ct)
#pragma unroll
            for (int ks = 0; ks < 2; ++ks)
                vv[ct][ks] = *reinterpret_cast<const bf16x8*>(&vT_s[h][16 * ct + lc][32 * ks + 8 * lg]);

        // ---- softmax: lane-local tree + 2 shfl for max and sum ----
        float vals[4][4];
#pragma unroll
        for (int t = 0; t < 4; ++t)
#pragma unroll
            for (int r = 0; r < 4; ++r)
                vals[t][r] = acc[t][r] + bias_v[t][r] + maddf[t][r];

        float mx[4];
#pragma unroll
        for (int t = 0; t < 4; ++t)
            mx[t] = fmaxf(fmaxf(vals[t][0], vals[t][1]), fmaxf(vals[t][2], vals[t][3]));
        float m = fmaxf(fmaxf(mx[0], mx[1]), fmaxf(mx[2], mx[3]));
        m = fmaxf(m, __shfl_xor(m, 16));
        m = fmaxf(m, __shfl_xor(m, 32));

        float e[4][4];
        float s = 0.f;
#pragma unroll
        for (int t = 0; t < 4; ++t) {
            float st = 0.f;
#pragma unroll
            for (int r = 0; r < 4; ++r) { e[t][r] = __expf(vals[t][r] - m); st += e[t][r]; }
            s += st;
        }
        s += __shfl_xor(s, 16);
        s += __shfl_xor(s, 32);
        const float rs = 1.0f / s;

        // ---- packed P store into wave-private stripe (no sync needed) ----
        {
            u16* prow = &p_s[wv][lc][4 * lg];
#pragma unroll
            for (int t = 0; t < 4; ++t) {
                ushort4 pk;
                pk.x = bfr(e[t][0] * rs); pk.y = bfr(e[t][1] * rs);
                pk.z = bfr(e[t][2] * rs); pk.w = bfr(e[t][3] * rs);
                *reinterpret_cast<ushort4*>(prow + 16 * t) = pk;
            }
        }

        // ---- PV: x_h[16x32] per wave ----
        f32x4 xacc[2] = {fzero, fzero};
#pragma unroll
        for (int ks = 0; ks < 2; ++ks) {
            const bf16x8 pa = *reinterpret_cast<const bf16x8*>(&p_s[wv][lc][32 * ks + 8 * lg]);
#pragma unroll
            for (int ct = 0; ct < 2; ++ct)
                xacc[ct] = __builtin_amdgcn_mfma_f32_16x16x32_bf16(pa, vv[ct][ks], xacc[ct], 0, 0, 0);
        }

        // ---- x_h C-layout -> A-fragment via wave-private stripe ----
#pragma unroll
        for (int ct = 0; ct < 2; ++ct)
#pragma unroll
            for (int r = 0; r < 4; ++r)
                p_s[wv][4 * lg + r][16 * ct + lc] = bfr(xacc[ct][r]);
        af[h] = *reinterpret_cast<const bf16x8*>(&p_s[wv][lc][8 * lg]);
    }

    // ---- proj tail (wave-private af): out rows 16wv.., all 192 cols ----
    f32x4 pacc[12];
#pragma unroll
    for (int ct = 0; ct < 12; ++ct) pacc[ct] = fzero;

#pragma unroll
    for (int ks = 0; ks < NH; ++ks) {
#pragma unroll
        for (int ct = 0; ct < 12; ++ct) {
            const bf16x8 bw = *reinterpret_cast<const bf16x8*>(wb + (16 * ct + lc) * CDIM + ks * 32 + 8 * lg);
            pacc[ct] = __builtin_amdgcn_mfma_f32_16x16x32_bf16(af[ks], bw, pacc[ct], 0, 0, 0);
        }
    }

#pragma unroll
    for (int ct = 0; ct < 12; ++ct) {
        const int c = 16 * ct + lc;
        const float pb = proj_b[c];
#pragma unroll
        for (int r = 0; r < 4; ++r) {
            const int i = 16 * wv + 4 * lg + r;
            if (i < NTOK)
                out[(size_t)b * (NTOK * CDIM) + i * CDIM + c] = pacc[ct][r] + pb;
        }
    }
}

extern "C" void kernel_launch(void* const* d_in, const int* in_sizes, int n_in,
                              void* d_out, int out_size, void* d_ws, size_t ws_size,
                              hipStream_t stream) {
    const float* qkv        = (const float*)d_in[0];
    const int*   rpi        = (const int*)d_in[1];
    const float* mask       = (const float*)d_in[2];
    const float* bias_table = (const float*)d_in[3];
    const float* proj_w     = (const float*)d_in[4];
    const float* proj_b     = (const float*)d_in[5];
    float* out = (float*)d_out;
    u16* wb = (u16*)d_ws;  // bf16 copy of proj_w (73728 B)

    const int nblk = in_sizes[0] / (NTOK * 3 * CDIM);  // 8192 windows

    build_wb<<<(CDIM * CDIM + 255) / 256, 256, 0, stream>>>(proj_w, wb);
    swin_fused<<<nblk, 256, 0, stream>>>(qkv, rpi, mask, bias_table, wb, proj_b, out);
}